// Round 21
// baseline (110.048 us; speedup 1.0000x reference)
//
#include <hip/hip_runtime.h>
#include <hip/hip_bf16.h>
#include <hip/hip_fp16.h>

#define N_NODES_C 100000
#define NSCAN     102400
#define NBKT      256        // coarse buckets, key = dst >> 9 (196 used)
#define NBLK      512        // partition blocks

// ---------------------------------------------------------------------------
// fp16 helpers
// ---------------------------------------------------------------------------
union U2H { unsigned u; __half2 h; };

typedef _Float16 h2v __attribute__((ext_vector_type(2)));   // for fdot2
typedef __fp16   p2v __attribute__((ext_vector_type(2)));   // cvt_pkrtz result
union U2HV { unsigned u; h2v h; };
union U2PV { unsigned u; p2v p; };

__device__ __forceinline__ __half2 addp(__half2 a, unsigned u)
{
    U2H c; c.u = u;
    return __hadd2(a, c.h);
}

__device__ __forceinline__ __half2 shfl_xor_h2(__half2 v, int m)
{
    U2H c; c.h = v;
    c.u = (unsigned)__shfl_xor((int)c.u, m, 64);
    return c.h;
}

__device__ __forceinline__ float dot2(unsigned xu, unsigned wu, float c)
{
#if __has_builtin(__builtin_amdgcn_fdot2)
    U2HV a, b;
    a.u = xu; b.u = wu;
    return __builtin_amdgcn_fdot2(a.h, b.h, c, false);
#else
    asm("v_dot2_f32_f16 %0, %1, %2, %0" : "+v"(c) : "v"(xu), "v"(wu));
    return c;
#endif
}

__device__ __forceinline__ uint4 pk8(float4 f0, float4 f1)
{
    U2PV a, b, c, d;
    a.p = __builtin_amdgcn_cvt_pkrtz(f0.x, f0.y);
    b.p = __builtin_amdgcn_cvt_pkrtz(f0.z, f0.w);
    c.p = __builtin_amdgcn_cvt_pkrtz(f1.x, f1.y);
    d.p = __builtin_amdgcn_cvt_pkrtz(f1.z, f1.w);
    return make_uint4(a.u, b.u, c.u, d.u);
}

// chunk per partition block, multiple of 4 so int4 loads stay aligned and
// fusedA0-hist / partA2 cover identical ranges.
__device__ __forceinline__ int part_chunk(int n_edges)
{
    return (((n_edges + NBLK - 1) / NBLK) + 3) & ~3;
}

// ---------------------------------------------------------------------------
// Fused: h_src f32 -> packed fp16 (blocks [0, nConv)), pad row N = zeros;
// per-block bucket histogram (int4 edge loads) -> count matrix, no atomics.
// ---------------------------------------------------------------------------
__global__ __launch_bounds__(256) void fusedA0(
    const float* __restrict__ x, uint4* __restrict__ y, int n8,
    const int* __restrict__ dst, int* __restrict__ bucket_cnt, int n_edges,
    int nConv)
{
    __shared__ int h[NBKT];
    int t = threadIdx.x;
    if ((int)blockIdx.x < nConv) {
        int i = blockIdx.x * 256 + t;
        if (i >= n8 + 8) return;
        if (i >= n8) { y[i] = make_uint4(0u, 0u, 0u, 0u); return; }
        const float4* x4 = reinterpret_cast<const float4*>(x);
        float4 a = x4[i * 2 + 0];
        float4 b = x4[i * 2 + 1];
        U2H c0, c1, c2, c3;
        c0.h = __floats2half2_rn(a.x, a.y);
        c1.h = __floats2half2_rn(a.z, a.w);
        c2.h = __floats2half2_rn(b.x, b.y);
        c3.h = __floats2half2_rn(b.z, b.w);
        uint4 o;
        o.x = c0.u; o.y = c1.u; o.z = c2.u; o.w = c3.u;
        y[i] = o;
    } else {
        int blk = blockIdx.x - nConv;
        h[t] = 0;
        __syncthreads();
        int chunk = part_chunk(n_edges);
        int start = blk * chunk;
        int end   = min(start + chunk, n_edges);
        if (start < end) {
            int nv = (end - start) >> 2;
            const int4* d4 = reinterpret_cast<const int4*>(dst + start);
            for (int k = t; k < nv; k += 256) {
                int4 d = d4[k];
                atomicAdd(&h[d.x >> 9], 1);
                atomicAdd(&h[d.y >> 9], 1);
                atomicAdd(&h[d.z >> 9], 1);
                atomicAdd(&h[d.w >> 9], 1);
            }
            for (int e = start + (nv << 2) + t; e < end; e += 256)
                atomicAdd(&h[dst[e] >> 9], 1);
        }
        __syncthreads();
        bucket_cnt[blk * NBKT + t] = h[t];
    }
}

// A1a: bucket totals (column sums of count matrix) -> exclusive bucket_base.
__global__ __launch_bounds__(256) void partA1a(
    const int* __restrict__ bucket_cnt, int* __restrict__ bucket_base)
{
    int t = threadIdx.x;
    int v = 0;
    #pragma unroll 8
    for (int blk = 0; blk < NBLK; ++blk)
        v += bucket_cnt[blk * NBKT + t];
    int incl = v;
    #pragma unroll
    for (int off = 1; off < 64; off <<= 1) {
        int u = __shfl_up(incl, off, 64);
        if ((t & 63) >= off) incl += u;
    }
    __shared__ int wsum[4];
    if ((t & 63) == 63) wsum[t >> 6] = incl;
    __syncthreads();
    int add = 0;
    for (int w = 0; w < (t >> 6); ++w) add += wsum[w];
    incl += add;
    bucket_base[t] = incl - v;
    if (t == 255) bucket_base[256] = incl;
}

// A1b: per-bucket exclusive scan over the 512 block counts -> blk_base.
__global__ __launch_bounds__(256) void partA1b(
    const int* __restrict__ bucket_cnt, const int* __restrict__ bucket_base,
    int* __restrict__ blk_base)
{
    __shared__ int c[512];
    __shared__ int sA[512], sB[512];
    int t = threadIdx.x;
    int b = blockIdx.x;
    c[t]       = bucket_cnt[t * NBKT + b];
    c[t + 256] = bucket_cnt[(t + 256) * NBKT + b];
    __syncthreads();
    sA[t] = c[t]; sA[t + 256] = c[t + 256];
    __syncthreads();
    int* pin  = sA;
    int* pout = sB;
    for (int off = 1; off < 512; off <<= 1) {
        int a0 = pin[t];
        if (t >= off) a0 += pin[t - off];
        int a1 = pin[t + 256] + pin[t + 256 - off];
        pout[t] = a0; pout[t + 256] = a1;
        __syncthreads();
        int* tmp = pin; pin = pout; pout = tmp;
    }
    int base = bucket_base[b];
    blk_base[b * NBLK + t]       = base + pin[t] - c[t];
    blk_base[b * NBLK + t + 256] = base + pin[t + 256] - c[t + 256];
}

// A2: single-pass scatter with int4 edge loads. No global atomics.
__global__ __launch_bounds__(256) void partA2(
    const int* __restrict__ src, const int* __restrict__ dst,
    const int* __restrict__ blk_base, int* __restrict__ packed, int n_edges)
{
    __shared__ int lcur[NBKT];
    int t = threadIdx.x;
    int blk = blockIdx.x;
    lcur[t] = blk_base[t * NBLK + blk];
    __syncthreads();
    int chunk = part_chunk(n_edges);
    int start = blk * chunk;
    int end   = min(start + chunk, n_edges);
    if (start >= end) return;
    int nv = (end - start) >> 2;
    const int4* d4 = reinterpret_cast<const int4*>(dst + start);
    const int4* s4 = reinterpret_cast<const int4*>(src + start);
    for (int k = t; k < nv; k += 256) {
        int4 d = d4[k];
        int4 s = s4[k];
        int p0 = atomicAdd(&lcur[d.x >> 9], 1);
        packed[p0] = (s.x << 9) | (d.x & 511);
        int p1 = atomicAdd(&lcur[d.y >> 9], 1);
        packed[p1] = (s.y << 9) | (d.y & 511);
        int p2 = atomicAdd(&lcur[d.z >> 9], 1);
        packed[p2] = (s.z << 9) | (d.z & 511);
        int p3 = atomicAdd(&lcur[d.w >> 9], 1);
        packed[p3] = (s.w << 9) | (d.w & 511);
    }
    for (int e = start + (nv << 2) + t; e < end; e += 256) {
        int d = dst[e];
        int pos = atomicAdd(&lcur[d >> 9], 1);
        packed[pos] = (src[e] << 9) | (d & 511);
    }
}

// B: one block per bucket. int4 passes over packed. LDS scan -> CSR offsets
// + scatter edge_src into the bucket's contiguous region.
__global__ __launch_bounds__(256) void partB(
    const int* __restrict__ packed, const int* __restrict__ bucket_base,
    int* __restrict__ offsets, int* __restrict__ edge_src)
{
    __shared__ int cnt[512];
    __shared__ int sA[512], sB[512];
    int t = threadIdx.x;
    int k = blockIdx.x;
    int b0 = bucket_base[k];
    int b1 = bucket_base[k + 1];

    int a0 = (b0 + 3) & ~3;          // aligned vector start
    int a1 = b1 & ~3;                // aligned vector end
    if (a1 < a0) a1 = a0;
    int headlen = min(a0, b1) - b0;  // <= 3
    int nv = (a1 - a0) >> 2;
    const int4* p4 = reinterpret_cast<const int4*>(packed + a0);

    cnt[t] = 0; cnt[t + 256] = 0;
    __syncthreads();
    if (t < headlen) atomicAdd(&cnt[packed[b0 + t] & 511], 1);
    for (int kk = t; kk < nv; kk += 256) {
        int4 p = p4[kk];
        atomicAdd(&cnt[p.x & 511], 1);
        atomicAdd(&cnt[p.y & 511], 1);
        atomicAdd(&cnt[p.z & 511], 1);
        atomicAdd(&cnt[p.w & 511], 1);
    }
    for (int i = a1 + t; i < b1; i += 256)
        atomicAdd(&cnt[packed[i] & 511], 1);
    __syncthreads();

    sA[t] = cnt[t]; sA[t + 256] = cnt[t + 256];
    __syncthreads();
    int* pin  = sA;
    int* pout = sB;
    for (int off = 1; off < 512; off <<= 1) {
        int v0 = pin[t];
        if (t >= off) v0 += pin[t - off];
        int v1 = pin[t + 256] + pin[t + 256 - off];
        pout[t] = v0; pout[t + 256] = v1;
        __syncthreads();
        int* tmp = pin; pin = pout; pout = tmp;
    }

    {
        int j0 = t, j1 = t + 256;
        int e0 = pin[j0] - cnt[j0];
        int e1 = pin[j1] - cnt[j1];
        offsets[k * 512 + j0] = b0 + e0;
        offsets[k * 512 + j1] = b0 + e1;
        cnt[j0] = b0 + e0;
        cnt[j1] = b0 + e1;
    }
    __syncthreads();

    if (t < headlen) {
        int p = packed[b0 + t];
        int pos = atomicAdd(&cnt[p & 511], 1);
        edge_src[pos] = p >> 9;
    }
    for (int kk = t; kk < nv; kk += 256) {
        int4 p = p4[kk];
        int pos;
        pos = atomicAdd(&cnt[p.x & 511], 1); edge_src[pos] = p.x >> 9;
        pos = atomicAdd(&cnt[p.y & 511], 1); edge_src[pos] = p.y >> 9;
        pos = atomicAdd(&cnt[p.z & 511], 1); edge_src[pos] = p.z >> 9;
        pos = atomicAdd(&cnt[p.w & 511], 1); edge_src[pos] = p.w >> 9;
    }
    for (int i = a1 + t; i < b1; i += 256) {
        int p = packed[i];
        int pos = atomicAdd(&cnt[p & 511], 1);
        edge_src[pos] = p >> 9;
    }
}

// ---------------------------------------------------------------------------
// Gather: ONE WAVE PER NODE, 2-deep unrolled edge loop.
// Tail clamp -> zero pad row (index N).
// ---------------------------------------------------------------------------
__global__ __launch_bounds__(256) void sage_gather(
    const uint4* __restrict__ hsb,
    const int*   __restrict__ offsets,
    const int*   __restrict__ edge_src,
    uint4*       __restrict__ meanh,
    int n_nodes)
{
    int wid  = (blockIdx.x * 256 + threadIdx.x) >> 6;
    int lane = threadIdx.x & 63;
    int slot = lane >> 3;
    int chunk = lane & 7;

    int e0  = offsets[wid];
    int e1  = offsets[wid + 1];
    int deg = e1 - e0;
    int nit = (deg + 7) >> 3;

    __half2 a0, a1, a2, a3;
    {
        U2H z; z.u = 0u;
        a0 = z.h; a1 = z.h; a2 = z.h; a3 = z.h;
    }

    int it = 0;
    for (; it + 2 <= nit; it += 2) {
        int iA = e0 + (it << 3) + slot;
        int iB = iA + 8;
        int sA_ = edge_src[iA];
        int sB_ = (iB < e1) ? edge_src[iB] : N_NODES_C;
        uint4 vA = hsb[(size_t)sA_ * 8 + chunk];
        uint4 vB = hsb[(size_t)sB_ * 8 + chunk];
        a0 = addp(a0, vA.x); a1 = addp(a1, vA.y);
        a2 = addp(a2, vA.z); a3 = addp(a3, vA.w);
        a0 = addp(a0, vB.x); a1 = addp(a1, vB.y);
        a2 = addp(a2, vB.z); a3 = addp(a3, vB.w);
    }
    if (it < nit) {
        int idx = e0 + (it << 3) + slot;
        int s = (idx < e1) ? edge_src[idx] : N_NODES_C;
        uint4 v = hsb[(size_t)s * 8 + chunk];
        a0 = addp(a0, v.x);
        a1 = addp(a1, v.y);
        a2 = addp(a2, v.z);
        a3 = addp(a3, v.w);
    }

    #pragma unroll
    for (int m = 8; m < 64; m <<= 1) {
        a0 = __hadd2(a0, shfl_xor_h2(a0, m));
        a1 = __hadd2(a1, shfl_xor_h2(a1, m));
        a2 = __hadd2(a2, shfl_xor_h2(a2, m));
        a3 = __hadd2(a3, shfl_xor_h2(a3, m));
    }

    if (lane < 8) {
        float invd = 1.0f / (float)(deg > 1 ? deg : 1);
        U2H o0, o1, o2, o3;
        o0.h = __floats2half2_rn(__low2float(a0) * invd, __high2float(a0) * invd);
        o1.h = __floats2half2_rn(__low2float(a1) * invd, __high2float(a1) * invd);
        o2.h = __floats2half2_rn(__low2float(a2) * invd, __high2float(a2) * invd);
        o3.h = __floats2half2_rn(__low2float(a3) * invd, __high2float(a3) * invd);
        meanh[(size_t)wid * 8 + lane] = make_uint4(o0.u, o1.u, o2.u, o3.u);
    }
}

// ---------------------------------------------------------------------------
// GEMM epilogue v3: 128-node tile. X (32KB) + W (16KB) packed fp16 in LDS,
// v_dot2_f32_f16 inner loop, acc[8][4] per thread. xq reads are m-group
// broadcasts (free), so doubling rows amortizes wq reads + W staging:
// 192 ds_reads/thread for 2x the nodes = 25% fewer LDS reads per output.
// ---------------------------------------------------------------------------
__global__ __launch_bounds__(256) void sage_gemm(
    const float* __restrict__ h_dst,
    const uint4* __restrict__ meanh,
    const float* __restrict__ weight,
    const float* __restrict__ bias,
    float*       __restrict__ out,
    int n_nodes)
{
    __shared__ uint4 xh4[128 * 16];  // x row r: col c4 at r*16+((c4+r)&15)
    __shared__ uint4 wh4[64 * 16];   // w row o: col c4 at o*16+((c4+(o>>2))&15)

    const int t    = threadIdx.x;
    const int base = blockIdx.x * 128;

    const float4* w4g = reinterpret_cast<const float4*>(weight);
    const float4* hd4 = reinterpret_cast<const float4*>(h_dst);

    // stage W as fp16: 4 uint4 per thread
    #pragma unroll
    for (int q = 0; q < 4; ++q) {
        int idx = t + q * 256;        // 0..1023
        int o   = idx >> 4;
        int c4  = idx & 15;
        float4 f0 = w4g[o * 32 + c4 * 2 + 0];
        float4 f1 = w4g[o * 32 + c4 * 2 + 1];
        wh4[o * 16 + ((c4 + (o >> 2)) & 15)] = pk8(f0, f1);
    }

    // stage h_dst (c4 = 0..7) as fp16: 4 uint4 per thread (128 rows)
    #pragma unroll
    for (int q = 0; q < 4; ++q) {
        int idx = t + q * 256;        // 0..1023
        int r   = idx >> 3;
        int c4  = idx & 7;
        int g   = base + r;
        float4 f0 = make_float4(0.f, 0.f, 0.f, 0.f);
        float4 f1 = f0;
        if (g < n_nodes) {
            f0 = hd4[(size_t)g * 16 + c4 * 2 + 0];
            f1 = hd4[(size_t)g * 16 + c4 * 2 + 1];
        }
        xh4[r * 16 + ((c4 + r) & 15)] = pk8(f0, f1);
    }

    // stage mean (c4 = 8..15), already fp16: 4 uint4 per thread (128 rows)
    #pragma unroll
    for (int q = 0; q < 4; ++q) {
        int idx = t + q * 256;        // 0..1023
        int r   = idx >> 3;
        int c8  = idx & 7;
        int g   = base + r;
        uint4 mv = make_uint4(0u, 0u, 0u, 0u);
        if (g < n_nodes)
            mv = meanh[(size_t)g * 8 + c8];
        xh4[r * 16 + (((8 + c8) + r) & 15)] = mv;
    }
    __syncthreads();

    const int m  = t & 15;    // out-group: o0 = 4m
    const int r0 = t >> 4;    // node base: rows r0 + 16*i, i<8
    const int o0 = m * 4;

    float4 bv = reinterpret_cast<const float4*>(bias)[m];

    float acc[8][4];
    #pragma unroll
    for (int i = 0; i < 8; ++i) {
        acc[i][0] = bv.x; acc[i][1] = bv.y; acc[i][2] = bv.z; acc[i][3] = bv.w;
    }

    #pragma unroll 2
    for (int c4 = 0; c4 < 16; ++c4) {
        uint4 wq[4];
        #pragma unroll
        for (int jj = 0; jj < 4; ++jj) {
            int o = o0 + jj;                      // (o>>2) == m for all jj
            wq[jj] = wh4[o * 16 + ((c4 + m) & 15)];
        }
        #pragma unroll
        for (int i = 0; i < 8; ++i) {
            int r = r0 + 16 * i;
            uint4 xq = xh4[r * 16 + ((c4 + r) & 15)];
            #pragma unroll
            for (int jj = 0; jj < 4; ++jj) {
                float a = acc[i][jj];
                a = dot2(xq.x, wq[jj].x, a);
                a = dot2(xq.y, wq[jj].y, a);
                a = dot2(xq.z, wq[jj].z, a);
                a = dot2(xq.w, wq[jj].w, a);
                acc[i][jj] = a;
            }
        }
    }

    #pragma unroll
    for (int i = 0; i < 8; ++i) {
        int g = base + r0 + 16 * i;
        if (g < n_nodes) {
            float4 ov = make_float4(acc[i][0], acc[i][1], acc[i][2], acc[i][3]);
            reinterpret_cast<float4*>(out)[(size_t)g * 16 + m] = ov;
        }
    }
}

// ---------------------------------------------------------------------------
extern "C" void kernel_launch(void* const* d_in, const int* in_sizes, int n_in,
                              void* d_out, int out_size, void* d_ws, size_t ws_size,
                              hipStream_t stream)
{
    const float* h_src  = (const float*)d_in[0];
    const float* h_dst  = (const float*)d_in[1];
    const int*   src    = (const int*)d_in[2];
    const int*   dst    = (const int*)d_in[3];
    const float* weight = (const float*)d_in[4];
    const float* bias   = (const float*)d_in[5];
    float*       out    = (float*)d_out;

    const int n_edges = in_sizes[2];
    const int n_feat  = in_sizes[0];   // N*64 floats

    // workspace layout (ints); hsb base 16B-aligned
    int*   bucket_cnt  = (int*)d_ws;                    // NBLK*NBKT
    int*   blk_base    = bucket_cnt + NBLK * NBKT;      // NBKT*NBLK
    int*   bucket_base = blk_base + NBKT * NBLK;        // 257 (pad 260)
    int*   packed      = bucket_base + 260;             // n_edges
    int*   edge_src    = packed + n_edges;              // n_edges + 64 slack
    uint4* hsb         = (uint4*)(edge_src + n_edges + 64);   // (N+1)*8
    uint4* meanh       = hsb + (size_t)(N_NODES_C + 1) * 8;   // N*8
    int*   offsets     = (int*)(meanh + (size_t)N_NODES_C * 8);  // NSCAN

    int n8 = n_feat / 8;   // 800000
    int nConv = (n8 + 8 + 255) / 256;

    fusedA0<<<nConv + NBLK, 256, 0, stream>>>(
        h_src, hsb, n8, dst, bucket_cnt, n_edges, nConv);
    partA1a<<<1, 256, 0, stream>>>(bucket_cnt, bucket_base);
    partA1b<<<NBKT, 256, 0, stream>>>(bucket_cnt, bucket_base, blk_base);
    partA2<<<NBLK, 256, 0, stream>>>(src, dst, blk_base, packed, n_edges);
    partB<<<(N_NODES_C + 511) / 512, 256, 0, stream>>>(
        packed, bucket_base, offsets, edge_src);

    sage_gather<<<N_NODES_C / 4, 256, 0, stream>>>(
        hsb, offsets, edge_src, meanh, N_NODES_C);

    sage_gemm<<<(N_NODES_C + 127) / 128, 256, 0, stream>>>(
        h_dst, meanh, weight, bias, out, N_NODES_C);
}

// Round 22
// 105.969 us; speedup vs baseline: 1.0385x; 1.0385x over previous
//
#include <hip/hip_runtime.h>
#include <hip/hip_bf16.h>
#include <hip/hip_fp16.h>

#define N_NODES_C 100000
#define NSCAN     102400
#define NBKT      256        // coarse buckets, key = dst >> 9 (196 used)
#define NBLK      512        // partition blocks

// ---------------------------------------------------------------------------
// fp16 helpers
// ---------------------------------------------------------------------------
union U2H { unsigned u; __half2 h; };

typedef _Float16 h2v __attribute__((ext_vector_type(2)));   // for fdot2
typedef __fp16   p2v __attribute__((ext_vector_type(2)));   // cvt_pkrtz result
union U2HV { unsigned u; h2v h; };
union U2PV { unsigned u; p2v p; };

__device__ __forceinline__ __half2 addp(__half2 a, unsigned u)
{
    U2H c; c.u = u;
    return __hadd2(a, c.h);
}

__device__ __forceinline__ __half2 shfl_xor_h2(__half2 v, int m)
{
    U2H c; c.h = v;
    c.u = (unsigned)__shfl_xor((int)c.u, m, 64);
    return c.h;
}

__device__ __forceinline__ float dot2(unsigned xu, unsigned wu, float c)
{
#if __has_builtin(__builtin_amdgcn_fdot2)
    U2HV a, b;
    a.u = xu; b.u = wu;
    return __builtin_amdgcn_fdot2(a.h, b.h, c, false);
#else
    asm("v_dot2_f32_f16 %0, %1, %2, %0" : "+v"(c) : "v"(xu), "v"(wu));
    return c;
#endif
}

__device__ __forceinline__ uint4 pk8(float4 f0, float4 f1)
{
    U2PV a, b, c, d;
    a.p = __builtin_amdgcn_cvt_pkrtz(f0.x, f0.y);
    b.p = __builtin_amdgcn_cvt_pkrtz(f0.z, f0.w);
    c.p = __builtin_amdgcn_cvt_pkrtz(f1.x, f1.y);
    d.p = __builtin_amdgcn_cvt_pkrtz(f1.z, f1.w);
    return make_uint4(a.u, b.u, c.u, d.u);
}

// chunk per partition block, multiple of 4 so int4 loads stay aligned and
// fusedA0-hist / partA2 cover identical ranges.
__device__ __forceinline__ int part_chunk(int n_edges)
{
    return (((n_edges + NBLK - 1) / NBLK) + 3) & ~3;
}

// ---------------------------------------------------------------------------
// Fused: h_src f32 -> packed fp16 (blocks [0, nConv)), pad row N = zeros;
// per-block bucket histogram (int4 edge loads) -> count matrix, no atomics.
// ---------------------------------------------------------------------------
__global__ __launch_bounds__(256) void fusedA0(
    const float* __restrict__ x, uint4* __restrict__ y, int n8,
    const int* __restrict__ dst, int* __restrict__ bucket_cnt, int n_edges,
    int nConv)
{
    __shared__ int h[NBKT];
    int t = threadIdx.x;
    if ((int)blockIdx.x < nConv) {
        int i = blockIdx.x * 256 + t;
        if (i >= n8 + 8) return;
        if (i >= n8) { y[i] = make_uint4(0u, 0u, 0u, 0u); return; }
        const float4* x4 = reinterpret_cast<const float4*>(x);
        float4 a = x4[i * 2 + 0];
        float4 b = x4[i * 2 + 1];
        U2H c0, c1, c2, c3;
        c0.h = __floats2half2_rn(a.x, a.y);
        c1.h = __floats2half2_rn(a.z, a.w);
        c2.h = __floats2half2_rn(b.x, b.y);
        c3.h = __floats2half2_rn(b.z, b.w);
        uint4 o;
        o.x = c0.u; o.y = c1.u; o.z = c2.u; o.w = c3.u;
        y[i] = o;
    } else {
        int blk = blockIdx.x - nConv;
        h[t] = 0;
        __syncthreads();
        int chunk = part_chunk(n_edges);
        int start = blk * chunk;
        int end   = min(start + chunk, n_edges);
        if (start < end) {
            int nv = (end - start) >> 2;
            const int4* d4 = reinterpret_cast<const int4*>(dst + start);
            for (int k = t; k < nv; k += 256) {
                int4 d = d4[k];
                atomicAdd(&h[d.x >> 9], 1);
                atomicAdd(&h[d.y >> 9], 1);
                atomicAdd(&h[d.z >> 9], 1);
                atomicAdd(&h[d.w >> 9], 1);
            }
            for (int e = start + (nv << 2) + t; e < end; e += 256)
                atomicAdd(&h[dst[e] >> 9], 1);
        }
        __syncthreads();
        bucket_cnt[blk * NBKT + t] = h[t];
    }
}

// A1a: bucket totals (column sums of count matrix) -> exclusive bucket_base.
__global__ __launch_bounds__(256) void partA1a(
    const int* __restrict__ bucket_cnt, int* __restrict__ bucket_base)
{
    int t = threadIdx.x;
    int v = 0;
    #pragma unroll 8
    for (int blk = 0; blk < NBLK; ++blk)
        v += bucket_cnt[blk * NBKT + t];
    int incl = v;
    #pragma unroll
    for (int off = 1; off < 64; off <<= 1) {
        int u = __shfl_up(incl, off, 64);
        if ((t & 63) >= off) incl += u;
    }
    __shared__ int wsum[4];
    if ((t & 63) == 63) wsum[t >> 6] = incl;
    __syncthreads();
    int add = 0;
    for (int w = 0; w < (t >> 6); ++w) add += wsum[w];
    incl += add;
    bucket_base[t] = incl - v;
    if (t == 255) bucket_base[256] = incl;
}

// A1b: per-bucket exclusive scan over the 512 block counts -> blk_base.
__global__ __launch_bounds__(256) void partA1b(
    const int* __restrict__ bucket_cnt, const int* __restrict__ bucket_base,
    int* __restrict__ blk_base)
{
    __shared__ int c[512];
    __shared__ int sA[512], sB[512];
    int t = threadIdx.x;
    int b = blockIdx.x;
    c[t]       = bucket_cnt[t * NBKT + b];
    c[t + 256] = bucket_cnt[(t + 256) * NBKT + b];
    __syncthreads();
    sA[t] = c[t]; sA[t + 256] = c[t + 256];
    __syncthreads();
    int* pin  = sA;
    int* pout = sB;
    for (int off = 1; off < 512; off <<= 1) {
        int a0 = pin[t];
        if (t >= off) a0 += pin[t - off];
        int a1 = pin[t + 256] + pin[t + 256 - off];
        pout[t] = a0; pout[t + 256] = a1;
        __syncthreads();
        int* tmp = pin; pin = pout; pout = tmp;
    }
    int base = bucket_base[b];
    blk_base[b * NBLK + t]       = base + pin[t] - c[t];
    blk_base[b * NBLK + t + 256] = base + pin[t + 256] - c[t + 256];
}

// A2: single-pass scatter with int4 edge loads. No global atomics.
__global__ __launch_bounds__(256) void partA2(
    const int* __restrict__ src, const int* __restrict__ dst,
    const int* __restrict__ blk_base, int* __restrict__ packed, int n_edges)
{
    __shared__ int lcur[NBKT];
    int t = threadIdx.x;
    int blk = blockIdx.x;
    lcur[t] = blk_base[t * NBLK + blk];
    __syncthreads();
    int chunk = part_chunk(n_edges);
    int start = blk * chunk;
    int end   = min(start + chunk, n_edges);
    if (start >= end) return;
    int nv = (end - start) >> 2;
    const int4* d4 = reinterpret_cast<const int4*>(dst + start);
    const int4* s4 = reinterpret_cast<const int4*>(src + start);
    for (int k = t; k < nv; k += 256) {
        int4 d = d4[k];
        int4 s = s4[k];
        int p0 = atomicAdd(&lcur[d.x >> 9], 1);
        packed[p0] = (s.x << 9) | (d.x & 511);
        int p1 = atomicAdd(&lcur[d.y >> 9], 1);
        packed[p1] = (s.y << 9) | (d.y & 511);
        int p2 = atomicAdd(&lcur[d.z >> 9], 1);
        packed[p2] = (s.z << 9) | (d.z & 511);
        int p3 = atomicAdd(&lcur[d.w >> 9], 1);
        packed[p3] = (s.w << 9) | (d.w & 511);
    }
    for (int e = start + (nv << 2) + t; e < end; e += 256) {
        int d = dst[e];
        int pos = atomicAdd(&lcur[d >> 9], 1);
        packed[pos] = (src[e] << 9) | (d & 511);
    }
}

// B: one block per bucket. int4 passes over packed. LDS scan -> CSR offsets
// + scatter edge_src into the bucket's contiguous region.
__global__ __launch_bounds__(256) void partB(
    const int* __restrict__ packed, const int* __restrict__ bucket_base,
    int* __restrict__ offsets, int* __restrict__ edge_src)
{
    __shared__ int cnt[512];
    __shared__ int sA[512], sB[512];
    int t = threadIdx.x;
    int k = blockIdx.x;
    int b0 = bucket_base[k];
    int b1 = bucket_base[k + 1];

    int a0 = (b0 + 3) & ~3;          // aligned vector start
    int a1 = b1 & ~3;                // aligned vector end
    if (a1 < a0) a1 = a0;
    int headlen = min(a0, b1) - b0;  // <= 3
    int nv = (a1 - a0) >> 2;
    const int4* p4 = reinterpret_cast<const int4*>(packed + a0);

    cnt[t] = 0; cnt[t + 256] = 0;
    __syncthreads();
    if (t < headlen) atomicAdd(&cnt[packed[b0 + t] & 511], 1);
    for (int kk = t; kk < nv; kk += 256) {
        int4 p = p4[kk];
        atomicAdd(&cnt[p.x & 511], 1);
        atomicAdd(&cnt[p.y & 511], 1);
        atomicAdd(&cnt[p.z & 511], 1);
        atomicAdd(&cnt[p.w & 511], 1);
    }
    for (int i = a1 + t; i < b1; i += 256)
        atomicAdd(&cnt[packed[i] & 511], 1);
    __syncthreads();

    sA[t] = cnt[t]; sA[t + 256] = cnt[t + 256];
    __syncthreads();
    int* pin  = sA;
    int* pout = sB;
    for (int off = 1; off < 512; off <<= 1) {
        int v0 = pin[t];
        if (t >= off) v0 += pin[t - off];
        int v1 = pin[t + 256] + pin[t + 256 - off];
        pout[t] = v0; pout[t + 256] = v1;
        __syncthreads();
        int* tmp = pin; pin = pout; pout = tmp;
    }

    {
        int j0 = t, j1 = t + 256;
        int e0 = pin[j0] - cnt[j0];
        int e1 = pin[j1] - cnt[j1];
        offsets[k * 512 + j0] = b0 + e0;
        offsets[k * 512 + j1] = b0 + e1;
        cnt[j0] = b0 + e0;
        cnt[j1] = b0 + e1;
    }
    __syncthreads();

    if (t < headlen) {
        int p = packed[b0 + t];
        int pos = atomicAdd(&cnt[p & 511], 1);
        edge_src[pos] = p >> 9;
    }
    for (int kk = t; kk < nv; kk += 256) {
        int4 p = p4[kk];
        int pos;
        pos = atomicAdd(&cnt[p.x & 511], 1); edge_src[pos] = p.x >> 9;
        pos = atomicAdd(&cnt[p.y & 511], 1); edge_src[pos] = p.y >> 9;
        pos = atomicAdd(&cnt[p.z & 511], 1); edge_src[pos] = p.z >> 9;
        pos = atomicAdd(&cnt[p.w & 511], 1); edge_src[pos] = p.w >> 9;
    }
    for (int i = a1 + t; i < b1; i += 256) {
        int p = packed[i];
        int pos = atomicAdd(&cnt[p & 511], 1);
        edge_src[pos] = p >> 9;
    }
}

// ---------------------------------------------------------------------------
// Gather: ONE WAVE PER NODE, 2-deep unrolled edge loop.
// Tail clamp -> zero pad row (index N).
// ---------------------------------------------------------------------------
__global__ __launch_bounds__(256) void sage_gather(
    const uint4* __restrict__ hsb,
    const int*   __restrict__ offsets,
    const int*   __restrict__ edge_src,
    uint4*       __restrict__ meanh,
    int n_nodes)
{
    int wid  = (blockIdx.x * 256 + threadIdx.x) >> 6;
    int lane = threadIdx.x & 63;
    int slot = lane >> 3;
    int chunk = lane & 7;

    int e0  = offsets[wid];
    int e1  = offsets[wid + 1];
    int deg = e1 - e0;
    int nit = (deg + 7) >> 3;

    __half2 a0, a1, a2, a3;
    {
        U2H z; z.u = 0u;
        a0 = z.h; a1 = z.h; a2 = z.h; a3 = z.h;
    }

    int it = 0;
    for (; it + 2 <= nit; it += 2) {
        int iA = e0 + (it << 3) + slot;
        int iB = iA + 8;
        int sA_ = edge_src[iA];
        int sB_ = (iB < e1) ? edge_src[iB] : N_NODES_C;
        uint4 vA = hsb[(size_t)sA_ * 8 + chunk];
        uint4 vB = hsb[(size_t)sB_ * 8 + chunk];
        a0 = addp(a0, vA.x); a1 = addp(a1, vA.y);
        a2 = addp(a2, vA.z); a3 = addp(a3, vA.w);
        a0 = addp(a0, vB.x); a1 = addp(a1, vB.y);
        a2 = addp(a2, vB.z); a3 = addp(a3, vB.w);
    }
    if (it < nit) {
        int idx = e0 + (it << 3) + slot;
        int s = (idx < e1) ? edge_src[idx] : N_NODES_C;
        uint4 v = hsb[(size_t)s * 8 + chunk];
        a0 = addp(a0, v.x);
        a1 = addp(a1, v.y);
        a2 = addp(a2, v.z);
        a3 = addp(a3, v.w);
    }

    #pragma unroll
    for (int m = 8; m < 64; m <<= 1) {
        a0 = __hadd2(a0, shfl_xor_h2(a0, m));
        a1 = __hadd2(a1, shfl_xor_h2(a1, m));
        a2 = __hadd2(a2, shfl_xor_h2(a2, m));
        a3 = __hadd2(a3, shfl_xor_h2(a3, m));
    }

    if (lane < 8) {
        float invd = 1.0f / (float)(deg > 1 ? deg : 1);
        U2H o0, o1, o2, o3;
        o0.h = __floats2half2_rn(__low2float(a0) * invd, __high2float(a0) * invd);
        o1.h = __floats2half2_rn(__low2float(a1) * invd, __high2float(a1) * invd);
        o2.h = __floats2half2_rn(__low2float(a2) * invd, __high2float(a2) * invd);
        o3.h = __floats2half2_rn(__low2float(a3) * invd, __high2float(a3) * invd);
        meanh[(size_t)wid * 8 + lane] = make_uint4(o0.u, o1.u, o2.u, o3.u);
    }
}

// ---------------------------------------------------------------------------
// GEMM epilogue (R20 config, measured 106us total): 64-node tile, X + W
// packed fp16 in LDS (16KB + 16KB), v_dot2_f32_f16 inner loop.
// R21's 128-node tile regressed (48KB LDS + acc[8][4] cut occupancy more
// than the 25% LDS-read saving gained) -- reverted.
// ---------------------------------------------------------------------------
__global__ __launch_bounds__(256) void sage_gemm(
    const float* __restrict__ h_dst,
    const uint4* __restrict__ meanh,
    const float* __restrict__ weight,
    const float* __restrict__ bias,
    float*       __restrict__ out,
    int n_nodes)
{
    __shared__ uint4 xh4[64 * 16];
    __shared__ uint4 wh4[64 * 16];

    const int t    = threadIdx.x;
    const int base = blockIdx.x * 64;

    const float4* w4g = reinterpret_cast<const float4*>(weight);
    const float4* hd4 = reinterpret_cast<const float4*>(h_dst);

    #pragma unroll
    for (int q = 0; q < 4; ++q) {
        int idx = t + q * 256;
        int o   = idx >> 4;
        int c4  = idx & 15;
        float4 f0 = w4g[o * 32 + c4 * 2 + 0];
        float4 f1 = w4g[o * 32 + c4 * 2 + 1];
        wh4[o * 16 + ((c4 + (o >> 2)) & 15)] = pk8(f0, f1);
    }

    #pragma unroll
    for (int q = 0; q < 2; ++q) {
        int idx = t + q * 256;
        int r   = idx >> 3;
        int c4  = idx & 7;
        int g   = base + r;
        float4 f0 = make_float4(0.f, 0.f, 0.f, 0.f);
        float4 f1 = f0;
        if (g < n_nodes) {
            f0 = hd4[(size_t)g * 16 + c4 * 2 + 0];
            f1 = hd4[(size_t)g * 16 + c4 * 2 + 1];
        }
        xh4[r * 16 + ((c4 + r) & 15)] = pk8(f0, f1);
    }

    #pragma unroll
    for (int q = 0; q < 2; ++q) {
        int idx = t + q * 256;
        int r   = idx >> 3;
        int c8  = idx & 7;
        int g   = base + r;
        uint4 mv = make_uint4(0u, 0u, 0u, 0u);
        if (g < n_nodes)
            mv = meanh[(size_t)g * 8 + c8];
        xh4[r * 16 + (((8 + c8) + r) & 15)] = mv;
    }
    __syncthreads();

    const int m  = t & 15;
    const int r0 = t >> 4;
    const int o0 = m * 4;

    float4 bv = reinterpret_cast<const float4*>(bias)[m];

    float acc[4][4];
    #pragma unroll
    for (int i = 0; i < 4; ++i) {
        acc[i][0] = bv.x; acc[i][1] = bv.y; acc[i][2] = bv.z; acc[i][3] = bv.w;
    }

    #pragma unroll 4
    for (int c4 = 0; c4 < 16; ++c4) {
        uint4 wq[4];
        #pragma unroll
        for (int jj = 0; jj < 4; ++jj) {
            int o = o0 + jj;
            wq[jj] = wh4[o * 16 + ((c4 + m) & 15)];
        }
        #pragma unroll
        for (int i = 0; i < 4; ++i) {
            int r = r0 + 16 * i;
            uint4 xq = xh4[r * 16 + ((c4 + r) & 15)];
            #pragma unroll
            for (int jj = 0; jj < 4; ++jj) {
                float a = acc[i][jj];
                a = dot2(xq.x, wq[jj].x, a);
                a = dot2(xq.y, wq[jj].y, a);
                a = dot2(xq.z, wq[jj].z, a);
                a = dot2(xq.w, wq[jj].w, a);
                acc[i][jj] = a;
            }
        }
    }

    #pragma unroll
    for (int i = 0; i < 4; ++i) {
        int g = base + r0 + 16 * i;
        if (g < n_nodes) {
            float4 ov = make_float4(acc[i][0], acc[i][1], acc[i][2], acc[i][3]);
            reinterpret_cast<float4*>(out)[(size_t)g * 16 + m] = ov;
        }
    }
}

// ---------------------------------------------------------------------------
extern "C" void kernel_launch(void* const* d_in, const int* in_sizes, int n_in,
                              void* d_out, int out_size, void* d_ws, size_t ws_size,
                              hipStream_t stream)
{
    const float* h_src  = (const float*)d_in[0];
    const float* h_dst  = (const float*)d_in[1];
    const int*   src    = (const int*)d_in[2];
    const int*   dst    = (const int*)d_in[3];
    const float* weight = (const float*)d_in[4];
    const float* bias   = (const float*)d_in[5];
    float*       out    = (float*)d_out;

    const int n_edges = in_sizes[2];
    const int n_feat  = in_sizes[0];   // N*64 floats

    // workspace layout (ints); hsb base 16B-aligned
    int*   bucket_cnt  = (int*)d_ws;                    // NBLK*NBKT
    int*   blk_base    = bucket_cnt + NBLK * NBKT;      // NBKT*NBLK
    int*   bucket_base = blk_base + NBKT * NBLK;        // 257 (pad 260)
    int*   packed      = bucket_base + 260;             // n_edges
    int*   edge_src    = packed + n_edges;              // n_edges + 64 slack
    uint4* hsb         = (uint4*)(edge_src + n_edges + 64);   // (N+1)*8
    uint4* meanh       = hsb + (size_t)(N_NODES_C + 1) * 8;   // N*8
    int*   offsets     = (int*)(meanh + (size_t)N_NODES_C * 8);  // NSCAN

    int n8 = n_feat / 8;   // 800000
    int nConv = (n8 + 8 + 255) / 256;

    fusedA0<<<nConv + NBLK, 256, 0, stream>>>(
        h_src, hsb, n8, dst, bucket_cnt, n_edges, nConv);
    partA1a<<<1, 256, 0, stream>>>(bucket_cnt, bucket_base);
    partA1b<<<NBKT, 256, 0, stream>>>(bucket_cnt, bucket_base, blk_base);
    partA2<<<NBLK, 256, 0, stream>>>(src, dst, blk_base, packed, n_edges);
    partB<<<(N_NODES_C + 511) / 512, 256, 0, stream>>>(
        packed, bucket_base, offsets, edge_src);

    sage_gather<<<N_NODES_C / 4, 256, 0, stream>>>(
        hsb, offsets, edge_src, meanh, N_NODES_C);

    sage_gemm<<<(N_NODES_C + 63) / 64, 256, 0, stream>>>(
        h_dst, meanh, weight, bias, out, N_NODES_C);
}